// Round 12
// baseline (868.527 us; speedup 1.0000x reference)
//
#include <hip/hip_runtime.h>
#include <cstdint>

#define N_NODES 100000
#define N_EDGES 500000
#define N_GRAPHS 128
#define HID 128
#define SCAN1_B ((2 * N_NODES + 255) / 256)   // 782 blocks over concatenated counts
#define N_HALF (N_EDGES / 32)                 // 15625 32-edge segments per layer

typedef __attribute__((ext_vector_type(8))) short short8;
typedef __attribute__((ext_vector_type(4))) float f32x4;

// ---- bf16 helpers ----
__device__ __forceinline__ unsigned pk_bf16(float a, float b) {
    unsigned ua = __float_as_uint(a);
    unsigned ub = __float_as_uint(b);
    ua = (ua + 0x7fffu + ((ua >> 16) & 1u)) >> 16;
    ub = (ub + 0x7fffu + ((ub >> 16) & 1u)) & 0xffff0000u;
    return ua | ub;
}
__device__ __forceinline__ ushort bf16r(float f) {
    unsigned u = __float_as_uint(f);
    return (ushort)((u + 0x7fffu + ((u >> 16) & 1u)) >> 16);
}
__device__ __forceinline__ float bf2f(ushort h) {
    return __uint_as_float((unsigned)h << 16);
}
// ---- 16-bit monotone encoding of bf16 for max; enc==0 unreachable for finite ----
__device__ __forceinline__ ushort encf16(float f) {   // f must be an exact bf16 value
    ushort h = bf16r(f);
    return (h & 0x8000) ? (ushort)(~h) : (ushort)(h | 0x8000);
}
__device__ __forceinline__ float decf16(ushort e) {
    ushort h = (e & 0x8000) ? (ushort)(e & 0x7FFF) : (ushort)(~e);
    return bf2f(h);
}
// 16-bit atomicMax via CAS on containing word; safe vs 16-bit plain stores to the
// other half (full-word compare forces retry on any concurrent change).
__device__ __forceinline__ void atomicMax16(ushort* addr, ushort val) {
    unsigned* word = (unsigned*)((size_t)addr & ~(size_t)3);
    unsigned shift = ((size_t)addr & 2) ? 16u : 0u;
    unsigned cur = *word;
    while (true) {
        ushort curh = (ushort)(cur >> shift);
        if (curh >= val) return;
        unsigned nw = (cur & ~(0xFFFFu << shift)) | ((unsigned)val << shift);
        unsigned prev = atomicCAS(word, cur, nw);
        if (prev == cur) return;
        cur = prev;
    }
}
// ---- fp32 monotone encoding (graph-level pooling only) ----
__device__ __forceinline__ unsigned encf(float f) {
    unsigned u = __float_as_uint(f);
    return (u & 0x80000000u) ? ~u : (u | 0x80000000u);
}
__device__ __forceinline__ float decf(unsigned e) {
    unsigned u = (e & 0x80000000u) ? (e & 0x7FFFFFFFu) : ~u;
    return __uint_as_float((e & 0x80000000u) ? (e & 0x7FFFFFFFu) : ~e);
}

// ---- transpose+convert weights -> bf16 [n][k], with D = Wa[128:256]-Wa[0:128]
//      computed on the fly; block 384 does the prep (wkey/bias0) work ----
__global__ __launch_bounds__(256) void transp_prep_kernel(const float* __restrict__ W1b,
                                                          const float* __restrict__ W2b,
                                                          const float* __restrict__ W1a,
                                                          const float* __restrict__ W2a,
                                                          const float* __restrict__ W_enc,
                                                          const float* __restrict__ b_enc,
                                                          const float* __restrict__ W0,
                                                          const float* __restrict__ b0,
                                                          ushort* __restrict__ WT,
                                                          float* __restrict__ wkey,
                                                          float* __restrict__ bias0) {
    int blk = blockIdx.x;
    int tid = threadIdx.x;
    if (blk >= 384) {   // prep
        if (tid < HID) {
            float wk = 0.f, bk = b0[tid];
            for (int k = 0; k < 32; ++k) {
                float w = W0[(15 + k) * HID + tid];
                wk += W_enc[k] * w;
                bk += b_enc[k] * w;
            }
            wkey[tid] = wk;
            bias0[tid] = bk;
        }
        return;
    }
    int m = blk >> 6;
    int i = (blk & 63) * 256 + tid;   // i = n*128 + k
    int n = i >> 7, k = i & 127;
    int src = k * HID + n;
    float v;
    switch (m) {
        case 0: v = W1b[src]; break;
        case 1: v = W2b[src]; break;
        case 2: v = W1a[src]; break;
        case 3: v = W1a[HID * HID + src] - W1a[src]; break;
        case 4: v = W2a[src]; break;
        default: v = W2a[HID * HID + src] - W2a[src]; break;
    }
    WT[m * HID * HID + i] = bf16r(v);
}

// ---- encoder: h = relu(features @ W0[0:15] + key*wkey + bias0) -> bf16 ----
__global__ __launch_bounds__(256) void encode_kernel(const float* __restrict__ x,
                                                     const float* __restrict__ W0,
                                                     const float* __restrict__ wkey,
                                                     const float* __restrict__ bias0,
                                                     ushort* __restrict__ h) {
    int n = blockIdx.x * 2 + (threadIdx.x >> 7);
    int j = threadIdx.x & 127;
    const float* xr = x + n * 16;
    float acc = bias0[j] + xr[0] * wkey[j];
#pragma unroll
    for (int f = 0; f < 15; ++f)
        acc = fmaf(xr[1 + f], W0[f * HID + j], acc);
    h[n * HID + j] = bf16r(fmaxf(acc, 0.f));
}

// ---- dual MFMA (N x 128 bf16) @ (128 x 128) -> bf16, LDS-restaged epilogue ----
// Optional fused combine (aggin u16-encoded): A-tile element becomes
// x1 = relu((cnt>0 ? dec16(agg)+badd : 0) + h), also written to xout.
__global__ __launch_bounds__(256, 4) void mm_mfma_dual_kernel(const ushort* __restrict__ in,
                                                              const ushort* __restrict__ aggin,
                                                              const int* __restrict__ cntin,
                                                              const float* __restrict__ baddin,
                                                              ushort* __restrict__ xout,
                                                              const ushort* __restrict__ WuT,
                                                              const ushort* __restrict__ WvT,
                                                              const float* __restrict__ bv,
                                                              ushort* __restrict__ outu,
                                                              ushort* __restrict__ outv, int nrows) {
    __shared__ ushort sH[128 * 136];   // A-tile, then reused for D-restage
    int tid = threadIdx.x;
    int n0 = blockIdx.x * 128;
#pragma unroll
    for (int q = 0; q < 8; ++q) {
        int c = q * 256 + tid;
        int r = c >> 4, off = (c & 15) << 3;
        int n = n0 + r;
        uint4 vv = make_uint4(0, 0, 0, 0);
        if (n < nrows) {
            uint4 hv = *(const uint4*)(in + (size_t)n * HID + off);
            if (aggin) {
                float add[8];
#pragma unroll
                for (int p = 0; p < 8; ++p) add[p] = 0.f;
                if (cntin[n] > 0) {
                    uint4 ev = *(const uint4*)(aggin + (size_t)n * HID + off);
                    unsigned ew[4] = {ev.x, ev.y, ev.z, ev.w};
#pragma unroll
                    for (int p = 0; p < 4; ++p) {
                        add[2 * p]     = decf16((ushort)(ew[p] & 0xffff)) + baddin[off + 2 * p];
                        add[2 * p + 1] = decf16((ushort)(ew[p] >> 16))    + baddin[off + 2 * p + 1];
                    }
                }
                unsigned hw[4] = {hv.x, hv.y, hv.z, hv.w};
                unsigned ow[4];
#pragma unroll
                for (int p = 0; p < 4; ++p) {
                    float lo = __uint_as_float(hw[p] << 16);
                    float hi = __uint_as_float(hw[p] & 0xffff0000u);
                    float r0 = fmaxf(add[2 * p] + lo, 0.f);
                    float r1 = fmaxf(add[2 * p + 1] + hi, 0.f);
                    ow[p] = pk_bf16(r0, r1);
                }
                vv = make_uint4(ow[0], ow[1], ow[2], ow[3]);
                *(uint4*)(xout + (size_t)n * HID + off) = vv;
            } else {
                vv = hv;
            }
        }
        *(uint4*)(sH + r * 136 + off) = vv;
    }
    __syncthreads();

    int lane = tid & 63, wv = tid >> 6;
    int l15 = lane & 15, quad = lane >> 4;

    short8 afr[2][4];
#pragma unroll
    for (int rr = 0; rr < 2; ++rr) {
        const ushort* ab = sH + (wv * 32 + rr * 16 + l15) * 136 + quad * 8;
#pragma unroll
        for (int kc = 0; kc < 4; ++kc)
            afr[rr][kc] = *(const short8*)(ab + kc * 32);
    }

#pragma unroll
    for (int pass = 0; pass < 2; ++pass) {
        const ushort* WT = pass ? WvT : WuT;
        ushort* out = pass ? outv : outu;
        f32x4 acc[2][8];
#pragma unroll
        for (int rr = 0; rr < 2; ++rr)
#pragma unroll
            for (int ct = 0; ct < 8; ++ct) acc[rr][ct] = (f32x4){0.f, 0.f, 0.f, 0.f};
#pragma unroll
        for (int kc = 0; kc < 4; ++kc) {
#pragma unroll
            for (int ct = 0; ct < 8; ++ct) {
                short8 bfr = *(const short8*)(WT + (ct * 16 + l15) * 128 + quad * 8 + kc * 32);
                acc[0][ct] = __builtin_amdgcn_mfma_f32_16x16x32_bf16(afr[0][kc], bfr, acc[0][ct], 0, 0, 0);
                acc[1][ct] = __builtin_amdgcn_mfma_f32_16x16x32_bf16(afr[1][kc], bfr, acc[1][ct], 0, 0, 0);
            }
        }
        __syncthreads();
#pragma unroll
        for (int ct = 0; ct < 8; ++ct) {
            int col = ct * 16 + l15;
            float bb = pass ? bv[col] : 0.f;
#pragma unroll
            for (int rr = 0; rr < 2; ++rr) {
                int rowb = wv * 32 + rr * 16 + quad * 4;
#pragma unroll
                for (int reg = 0; reg < 4; ++reg)
                    sH[(rowb + reg) * 136 + col] = bf16r(acc[rr][ct][reg] + bb);
            }
        }
        __syncthreads();
#pragma unroll
        for (int q = 0; q < 8; ++q) {
            int c = q * 256 + tid;
            int r = c >> 4, off = (c & 15) << 3;
            int m = n0 + r;
            if (m < nrows)
                *(uint4*)(out + (size_t)m * HID + off) = *(const uint4*)(sH + r * 136 + off);
        }
    }
}

// ---- merged CSR build for BOTH layers ----
__global__ __launch_bounds__(256) void hist_kernel(const int* __restrict__ dst1,
                                                   const int* __restrict__ dst2,
                                                   int* __restrict__ cnt) {
    int e = blockIdx.x * 256 + threadIdx.x;
    if (e < N_EDGES) atomicAdd(&cnt[dst1[e]], 1);
    else if (e < 2 * N_EDGES) atomicAdd(&cnt[N_NODES + dst2[e - N_EDGES]], 1);
}

__global__ __launch_bounds__(256) void scan1_kernel(const int* __restrict__ cnt,
                                                    int* __restrict__ cursor,
                                                    int* __restrict__ partials) {
    __shared__ int tmp[256];
    int tid = threadIdx.x;
    int gid = blockIdx.x * 256 + tid;
    int v = (gid < 2 * N_NODES) ? cnt[gid] : 0;
    tmp[tid] = v;
    __syncthreads();
#pragma unroll
    for (int off = 1; off < 256; off <<= 1) {
        int t = (tid >= off) ? tmp[tid - off] : 0;
        __syncthreads();
        tmp[tid] += t;
        __syncthreads();
    }
    if (gid < 2 * N_NODES) cursor[gid] = tmp[tid] - v;   // local exclusive
    if (tid == 255) partials[blockIdx.x] = tmp[255];
}

__global__ __launch_bounds__(1024) void scan2_kernel(int* __restrict__ partials) {
    __shared__ int tmp[1024];
    int tid = threadIdx.x;
    int v = (tid < SCAN1_B) ? partials[tid] : 0;
    tmp[tid] = v;
    __syncthreads();
#pragma unroll
    for (int off = 1; off < 1024; off <<= 1) {
        int t = (tid >= off) ? tmp[tid - off] : 0;
        __syncthreads();
        tmp[tid] += t;
        __syncthreads();
    }
    if (tid < SCAN1_B) partials[tid] = tmp[tid] - v;  // exclusive
}

__global__ __launch_bounds__(256) void scatter_kernel(const int* __restrict__ src1,
                                                      const int* __restrict__ dst1,
                                                      const int* __restrict__ src2,
                                                      const int* __restrict__ dst2,
                                                      int* __restrict__ cursor,
                                                      const int* __restrict__ partials,
                                                      int2* __restrict__ pedge) {
    int e = blockIdx.x * 256 + threadIdx.x;
    if (e < N_EDGES) {
        int d = dst1[e];
        int pos = atomicAdd(&cursor[d], 1) + partials[d >> 8];
        pedge[pos] = make_int2(src1[e], d);
    } else if (e < 2 * N_EDGES) {
        int d = dst2[e - N_EDGES];
        int idx = N_NODES + d;
        int pos = atomicAdd(&cursor[idx], 1) + partials[idx >> 8];
        pedge[pos] = make_int2(src2[e - N_EDGES], d);   // pos lands in [N_EDGES, 2*N_EDGES)
    }
}

// ---- zero boundary agg rows for BOTH layers in one launch (u16 arrays) ----
__global__ __launch_bounds__(256) void zbound_both_kernel(const int2* __restrict__ pedge,
                                                          ushort* __restrict__ agg1,
                                                          ushort* __restrict__ agg2) {
    int b = blockIdx.x * 4 + (threadIdx.x >> 6);
    int lane = threadIdx.x & 63;
    if (b >= 2 * N_HALF) return;
    int layer = b >= N_HALF;
    int bl = b - layer * N_HALF;
    const int2* pe = pedge + (size_t)layer * N_EDGES;
    ushort* agg = layer ? agg2 : agg1;
    int d;
    if (bl == 0) {
        d = pe[N_EDGES - 1].y;               // tail row (clamped duplicates -> atomics)
    } else {
        int da = pe[bl * 32 - 1].y, db = pe[bl * 32].y;
        if (da != db) return;
        d = db;
    }
    *(unsigned*)(agg + (size_t)d * HID + lane * 2) = 0u;   // 2 cols per lane
}

// ---- edge conv: bf16 MFMA, 128-edge dst-sorted windows, 512 threads, u16 agg ----
__global__ __launch_bounds__(512, 4) void edge_kernel(const ushort* __restrict__ u,
                                                      const ushort* __restrict__ v,
                                                      const float* __restrict__ x,
                                                      const int2* __restrict__ pedge,
                                                      const ushort* __restrict__ WbT,
                                                      const float* __restrict__ wlast,
                                                      ushort* __restrict__ agg) {
    __shared__ ushort sWT[128 * 136];   // 34816 B: WbT[n][k] bf16, padded stride
    __shared__ ushort sU[128 * 136];    // 34816 B union: t[128][136] then msgT[128][132]
    __shared__ int sSrc[128], sDst[128];
    __shared__ float sKd[128];
    __shared__ int sPrev, sNext;
    int tid = threadIdx.x;
    int w0 = blockIdx.x * 128;

#pragma unroll
    for (int q = 0; q < 4; ++q) {
        int c = q * 512 + tid;
        int n = c >> 4, off = (c & 15) << 3;
        *(uint4*)(sWT + n * 136 + off) = *(const uint4*)(WbT + n * 128 + off);
    }
    if (tid < 128) {
        int e = w0 + tid;
        if (e >= N_EDGES) e = N_EDGES - 1;   // clamp: idempotent under max (tail row pre-zeroed)
        int2 sd = pedge[e];
        sSrc[tid] = sd.x;
        sDst[tid] = sd.y;
        sKd[tid] = x[(size_t)sd.x * 16] - x[(size_t)sd.y * 16];
    }
    if (tid == 128) sPrev = (w0 > 0) ? pedge[w0 - 1].y : -1;
    if (tid == 129) sNext = (w0 + 128 < N_EDGES) ? pedge[w0 + 128].y : -1;
    __syncthreads();

    // phase 1: 4 threads/edge, 32 cols each (512 threads -> 128 edges)
    {
        int eloc = tid >> 2;
        int kb = (tid & 3) << 5;
        int s = sSrc[eloc], d = sDst[eloc];
        float kd = sKd[eloc];
        const uint4* ur = (const uint4*)(u + (size_t)s * HID + kb);
        const uint4* vr = (const uint4*)(v + (size_t)d * HID + kb);
        uint4 uu[4], vv[4];
#pragma unroll
        for (int q = 0; q < 4; ++q) uu[q] = ur[q];
#pragma unroll
        for (int q = 0; q < 4; ++q) vv[q] = vr[q];
        const float4* wr4 = (const float4*)(wlast + kb);
        uint4* tout = (uint4*)(sU + eloc * 136 + kb);
#pragma unroll
        for (int q = 0; q < 4; ++q) {
            float4 wa = wr4[2 * q], wb = wr4[2 * q + 1];
            float w[8] = {wa.x, wa.y, wa.z, wa.w, wb.x, wb.y, wb.z, wb.w};
            unsigned pu[4] = {uu[q].x, uu[q].y, uu[q].z, uu[q].w};
            unsigned pv[4] = {vv[q].x, vv[q].y, vv[q].z, vv[q].w};
            unsigned pk[4];
#pragma unroll
            for (int p = 0; p < 4; ++p) {
                float a0 = __uint_as_float(pu[p] << 16) + __uint_as_float(pv[p] << 16);
                float a1 = __uint_as_float(pu[p] & 0xffff0000u) + __uint_as_float(pv[p] & 0xffff0000u);
                a0 = fmaf(kd, w[2 * p], a0);
                a1 = fmaf(kd, w[2 * p + 1], a1);
                a0 = a0 > 0.f ? a0 : 0.1f * a0;
                a1 = a1 > 0.f ? a1 : 0.1f * a1;
                pk[p] = pk_bf16(a0, a1);
            }
            uint4 o; o.x = pk[0]; o.y = pk[1]; o.z = pk[2]; o.w = pk[3];
            tout[q] = o;
        }
    }
    __syncthreads();

    // phase 2: MFMA. wave wv (0..7) owns edges wv*16..+15; 8 col-tiles x 4 K-chunks
    int lane = tid & 63, wv = tid >> 6;
    int l15 = lane & 15, quad = lane >> 4;
    short8 afr[4];
    {
        const ushort* ab = sU + (wv * 16 + l15) * 136 + quad * 8;
#pragma unroll
        for (int kc = 0; kc < 4; ++kc)
            afr[kc] = *(const short8*)(ab + kc * 32);
    }
    f32x4 acc[8];
#pragma unroll
    for (int ct = 0; ct < 8; ++ct) {
        f32x4 a = {0.f, 0.f, 0.f, 0.f};
        const ushort* bb = sWT + (ct * 16 + l15) * 136 + quad * 8;
#pragma unroll
        for (int kc = 0; kc < 4; ++kc) {
            short8 bfr = *(const short8*)(bb + kc * 32);
            a = __builtin_amdgcn_mfma_f32_16x16x32_bf16(afr[kc], bfr, a, 0, 0, 0);
        }
        acc[ct] = a;
    }
    __syncthreads();   // all t reads done -> sU reusable

    // epilogue: msgT[col][edge] bf16, stride 132
#pragma unroll
    for (int ct = 0; ct < 8; ++ct) {
        uint2 pr;
        pr.x = pk_bf16(acc[ct][0], acc[ct][1]);
        pr.y = pk_bf16(acc[ct][2], acc[ct][3]);
        *(uint2*)(sU + (ct * 16 + l15) * 132 + wv * 16 + quad * 4) = pr;
    }
    __syncthreads();

    // phase 3: segmented max, 4 threads/col (quarter-window = 32 edges each), u16 agg
    {
        int j = tid & 127;
        int q4 = tid >> 7;            // 0..3
        int eBeg = q4 * 32;
        const ushort* mrow = sU + j * 132 + eBeg;
        float vals[32];
#pragma unroll
        for (int q = 0; q < 8; ++q) {
            ushort4 mv = *(const ushort4*)(mrow + q * 4);
            vals[q * 4 + 0] = bf2f(mv.x);
            vals[q * 4 + 1] = bf2f(mv.y);
            vals[q * 4 + 2] = bf2f(mv.z);
            vals[q * 4 + 3] = bf2f(mv.w);
        }
        int prevD = (q4 == 0) ? sPrev : sDst[eBeg - 1];
        int nextD = (q4 == 3) ? sNext : sDst[eBeg + 32];
        int cur = sDst[eBeg], rs = eBeg;
        float mx = vals[0];
        for (int e2 = 1; e2 < 32; ++e2) {
            int d = sDst[eBeg + e2];      // uniform across the quarter's lanes
            float vv2 = vals[e2];
            if (d != cur) {
                ushort en = encf16(mx);
                ushort* ap = agg + (size_t)cur * HID + j;
                if (rs == eBeg && cur == prevD) atomicMax16(ap, en);
                else *ap = en;
                cur = d; rs = eBeg + e2; mx = vv2;
            } else {
                mx = fmaxf(mx, vv2);
            }
        }
        ushort en = encf16(mx);
        ushort* ap = agg + (size_t)cur * HID + j;
        if ((rs == eBeg && cur == prevD) || cur == nextD) atomicMax16(ap, en);
        else *ap = en;
    }
}

// ---- pooling with fused layer-2 combine: x2 never materialized; u16 agg ----
__global__ __launch_bounds__(256) void pool_kernel(const ushort* __restrict__ x1,
                                                   const ushort* __restrict__ agg2,
                                                   const float* __restrict__ b2b,
                                                   const int* __restrict__ cnt2,
                                                   const int* __restrict__ batch,
                                                   float* __restrict__ pooled) {
    int g = blockIdx.x >> 3, s = blockIdx.x & 7;
    int tid = threadIdx.x;
    int lo = 0, hi = N_NODES;
    while (lo < hi) { int mid = (lo + hi) >> 1; if (batch[mid] < g) lo = mid + 1; else hi = mid; }
    int start = lo;
    hi = N_NODES;
    while (lo < hi) { int mid = (lo + hi) >> 1; if (batch[mid] < g + 1) lo = mid + 1; else hi = mid; }
    int end = lo;
    int cnt = end - start;
    int b0 = start + (int)((long long)cnt * s / 8);
    int b1 = start + (int)((long long)cnt * (s + 1) / 8);
    if (b1 <= b0) return;
    int j = tid & 127;
    bool isx2 = tid >= 128;
    float bbj = isx2 ? b2b[j] : 0.f;
    float mx = -INFINITY, sm = 0.f;
    for (int n = b0; n < b1; ++n) {
        float xv = bf2f(x1[(size_t)n * HID + j]);
        float vv;
        if (isx2) {
            float a = 0.f;
            if (cnt2[n] > 0) a = decf16(agg2[(size_t)n * HID + j]) + bbj;
            vv = fmaxf(a + xv, 0.f);
        } else {
            vv = xv;
        }
        mx = fmaxf(mx, vv);
        sm += vv;
    }
    atomicMax((unsigned*)pooled + (size_t)g * 512 + tid, encf(mx));
    atomicAdd(pooled + (size_t)g * 512 + 256 + tid, sm);
}

// ---- final MLP + log_softmax ----
__global__ __launch_bounds__(128) void final_kernel(const float* __restrict__ pooled,
                                                    const int* __restrict__ batch,
                                                    const float* __restrict__ Wf1,
                                                    const float* __restrict__ bf1,
                                                    const float* __restrict__ Wf2,
                                                    const float* __restrict__ bf2,
                                                    float* __restrict__ out) {
    __shared__ float sP[512];
    __shared__ float sH[128];
    int g = blockIdx.x, tid = threadIdx.x;
    int lo = 0, hi = N_NODES;
    while (lo < hi) { int mid = (lo + hi) >> 1; if (batch[mid] < g) lo = mid + 1; else hi = mid; }
    int start = lo;
    hi = N_NODES;
    while (lo < hi) { int mid = (lo + hi) >> 1; if (batch[mid] < g + 1) lo = mid + 1; else hi = mid; }
    int cnt = lo - start;
    float inv = 1.f / (float)(cnt > 1 ? cnt : 1);
#pragma unroll
    for (int q = 0; q < 4; ++q) {
        int idx = q * 128 + tid;
        float raw;
        if (idx < 256) {
            unsigned e = ((const unsigned*)pooled)[(size_t)g * 512 + idx];
            raw = (e == 0u) ? 0.f : decf(e);
        } else {
            raw = pooled[(size_t)g * 512 + idx] * inv;
        }
        sP[idx] = raw;
    }
    __syncthreads();
    float acc = bf1[tid];
    for (int k = 0; k < 512; ++k) acc = fmaf(sP[k], Wf1[k * HID + tid], acc);
    sH[tid] = fmaxf(acc, 0.f);
    __syncthreads();
    if (tid < 2) {
        float l = bf2[tid];
        for (int k = 0; k < 128; ++k) l = fmaf(sH[k], Wf2[k * 2 + tid], l);
        sP[tid] = l;
    }
    __syncthreads();
    if (tid == 0) {
        float l0 = sP[0], l1 = sP[1];
        float m = fmaxf(l0, l1);
        float ls = m + logf(expf(l0 - m) + expf(l1 - m));
        out[g * 2 + 0] = l0 - ls;
        out[g * 2 + 1] = l1 - ls;
    }
}

extern "C" void kernel_launch(void* const* d_in, const int* in_sizes, int n_in,
                              void* d_out, int out_size, void* d_ws, size_t ws_size,
                              hipStream_t stream) {
    const float* x     = (const float*)d_in[0];
    const float* W_enc = (const float*)d_in[1];
    const float* b_enc = (const float*)d_in[2];
    const float* W0    = (const float*)d_in[3];
    const float* b0    = (const float*)d_in[4];
    const float* W1a   = (const float*)d_in[5];
    const float* b1a   = (const float*)d_in[6];
    const float* W1b   = (const float*)d_in[7];
    const float* b1b   = (const float*)d_in[8];
    const float* W2a   = (const float*)d_in[9];
    const float* b2a   = (const float*)d_in[10];
    const float* W2b   = (const float*)d_in[11];
    const float* b2b   = (const float*)d_in[12];
    const float* Wf1   = (const float*)d_in[13];
    const float* bf1   = (const float*)d_in[14];
    const float* Wf2   = (const float*)d_in[15];
    const float* bf2   = (const float*)d_in[16];
    const int* src1    = (const int*)d_in[17];
    const int* dst1    = (const int*)d_in[18];
    const int* src2    = (const int*)d_in[19];
    const int* dst2    = (const int*)d_in[20];
    const int* batch   = (const int*)d_in[21];

    const size_t NB = (size_t)N_NODES * HID;     // 12.8M elements
    ushort* hbuf  = (ushort*)d_ws;               // h -> x1 (in place, bf16)
    ushort* agg1  = hbuf + NB;                   // layer-1 segment-max, u16 encoded
    ushort* agg2  = agg1 + NB;                   // layer-2 segment-max, u16 encoded
    ushort* ubuf  = agg2 + NB;                   // u bf16
    ushort* vbuf  = ubuf + NB;                   // v bf16
    ushort* WT    = vbuf + NB;                   // 6 x 16384 bf16: Wb1,Wb2,Wu1,Wv1,Wu2,Wv2
    ushort* WbT1 = WT;
    ushort* WbT2 = WT + 1 * HID * HID;
    ushort* WuT1 = WT + 2 * HID * HID;
    ushort* WvT1 = WT + 3 * HID * HID;
    ushort* WuT2 = WT + 4 * HID * HID;
    ushort* WvT2 = WT + 5 * HID * HID;
    float* wkey  = (float*)(WT + 6 * HID * HID);
    float* bias0 = wkey + 128;
    float* pooled = bias0 + 128;                 // 128*512 fp32
    int* cnt    = (int*)(pooled + 128 * 512);    // 2*N_NODES (both layers)
    int* cursor = cnt + 2 * N_NODES;             // 2*N_NODES
    int* partials = cursor + 2 * N_NODES;        // 1024
    int2* pedge = (int2*)(partials + 1024);      // 2*N_EDGES pairs (both layers)

    const int bothGrid = (2 * N_EDGES + 255) / 256;   // 3907
    const int edgeGrid = (N_EDGES + 127) / 128;       // 3907 windows of 128
    const int mmGrid   = (N_NODES + 127) / 128;       // 782
    const int zbGrid   = (2 * N_HALF + 3) / 4;        // 7813 (both layers)

    transp_prep_kernel<<<385, 256, 0, stream>>>(W1b, W2b, W1a, W2a, W_enc, b_enc, W0, b0,
                                                WT, wkey, bias0);
    encode_kernel<<<N_NODES / 2, 256, 0, stream>>>(x, W0, wkey, bias0, hbuf);

    // ---- merged CSR build (both layers) ----
    hipMemsetAsync(cnt, 0, 2 * N_NODES * sizeof(int), stream);
    hist_kernel<<<bothGrid, 256, 0, stream>>>(dst1, dst2, cnt);
    scan1_kernel<<<SCAN1_B, 256, 0, stream>>>(cnt, cursor, partials);
    scan2_kernel<<<1, 1024, 0, stream>>>(partials);
    scatter_kernel<<<bothGrid, 256, 0, stream>>>(src1, dst1, src2, dst2, cursor, partials, pedge);
    zbound_both_kernel<<<zbGrid, 256, 0, stream>>>(pedge, agg1, agg2);

    // ---- layer 1 ----
    mm_mfma_dual_kernel<<<mmGrid, 256, 0, stream>>>(hbuf, nullptr, nullptr, nullptr, nullptr,
                                                    WuT1, WvT1, b1a, ubuf, vbuf, N_NODES);
    edge_kernel<<<edgeGrid, 512, 0, stream>>>(ubuf, vbuf, x, pedge, WbT1, W1a + 256 * HID, agg1);

    // ---- layer 2 (mm fuses layer-1 combine; writes x1 to hbuf) ----
    mm_mfma_dual_kernel<<<mmGrid, 256, 0, stream>>>(hbuf, agg1, cnt, b1b, hbuf,
                                                    WuT2, WvT2, b2a, ubuf, vbuf, N_NODES);
    edge_kernel<<<edgeGrid, 512, 0, stream>>>(ubuf, vbuf, x, pedge + N_EDGES, WbT2, W2a + 256 * HID, agg2);

    // ---- pooling (layer-2 combine fused) + head ----
    hipMemsetAsync(pooled, 0, 128 * 512 * sizeof(float), stream);
    pool_kernel<<<N_GRAPHS * 8, 256, 0, stream>>>(hbuf, agg2, b2b, cnt + N_NODES, batch, pooled);
    final_kernel<<<N_GRAPHS, 128, 0, stream>>>(pooled, batch, Wf1, bf1, Wf2, bf2, (float*)d_out);
}

// Round 13
// 660.052 us; speedup vs baseline: 1.3158x; 1.3158x over previous
//
#include <hip/hip_runtime.h>
#include <cstdint>

#define N_NODES 100000
#define N_EDGES 500000
#define N_GRAPHS 128
#define HID 128
#define SCAN1_B ((2 * N_NODES + 255) / 256)   // 782 blocks over concatenated counts
#define N_HALF (N_EDGES / 32)                 // 15625 32-edge segments per layer

typedef __attribute__((ext_vector_type(8))) short short8;
typedef __attribute__((ext_vector_type(4))) float f32x4;

// ---- monotone float<->uint encoding for max; enc==0 marks "never written" ----
__device__ __forceinline__ unsigned encf(float f) {
    unsigned u = __float_as_uint(f);
    return (u & 0x80000000u) ? ~u : (u | 0x80000000u);
}
__device__ __forceinline__ float decf(unsigned e) {
    unsigned u = (e & 0x80000000u) ? (e & 0x7FFFFFFFu) : ~e;
    return __uint_as_float(u);
}
__device__ __forceinline__ unsigned pk_bf16(float a, float b) {
    unsigned ua = __float_as_uint(a);
    unsigned ub = __float_as_uint(b);
    ua = (ua + 0x7fffu + ((ua >> 16) & 1u)) >> 16;
    ub = (ub + 0x7fffu + ((ub >> 16) & 1u)) & 0xffff0000u;
    return ua | ub;
}
__device__ __forceinline__ ushort bf16r(float f) {
    unsigned u = __float_as_uint(f);
    return (ushort)((u + 0x7fffu + ((u >> 16) & 1u)) >> 16);
}
__device__ __forceinline__ float bf2f(ushort h) {
    return __uint_as_float((unsigned)h << 16);
}

// ---- transpose+convert weights -> bf16 [n][k], D computed on the fly;
//      block 384 does the prep (wkey/bias0) work ----
__global__ __launch_bounds__(256) void transp_prep_kernel(const float* __restrict__ W1b,
                                                          const float* __restrict__ W2b,
                                                          const float* __restrict__ W1a,
                                                          const float* __restrict__ W2a,
                                                          const float* __restrict__ W_enc,
                                                          const float* __restrict__ b_enc,
                                                          const float* __restrict__ W0,
                                                          const float* __restrict__ b0,
                                                          ushort* __restrict__ WT,
                                                          float* __restrict__ wkey,
                                                          float* __restrict__ bias0) {
    int blk = blockIdx.x;
    int tid = threadIdx.x;
    if (blk >= 384) {   // prep
        if (tid < HID) {
            float wk = 0.f, bk = b0[tid];
            for (int k = 0; k < 32; ++k) {
                float w = W0[(15 + k) * HID + tid];
                wk += W_enc[k] * w;
                bk += b_enc[k] * w;
            }
            wkey[tid] = wk;
            bias0[tid] = bk;
        }
        return;
    }
    int m = blk >> 6;
    int i = (blk & 63) * 256 + tid;   // i = n*128 + k
    int n = i >> 7, k = i & 127;
    int src = k * HID + n;
    float v;
    switch (m) {
        case 0: v = W1b[src]; break;
        case 1: v = W2b[src]; break;
        case 2: v = W1a[src]; break;
        case 3: v = W1a[HID * HID + src] - W1a[src]; break;
        case 4: v = W2a[src]; break;
        default: v = W2a[HID * HID + src] - W2a[src]; break;
    }
    WT[m * HID * HID + i] = bf16r(v);
}

// ---- encoder: h = relu(features @ W0[0:15] + key*wkey + bias0) -> bf16 ----
__global__ __launch_bounds__(256) void encode_kernel(const float* __restrict__ x,
                                                     const float* __restrict__ W0,
                                                     const float* __restrict__ wkey,
                                                     const float* __restrict__ bias0,
                                                     ushort* __restrict__ h) {
    int n = blockIdx.x * 2 + (threadIdx.x >> 7);
    int j = threadIdx.x & 127;
    const float* xr = x + n * 16;
    float acc = bias0[j] + xr[0] * wkey[j];
#pragma unroll
    for (int f = 0; f < 15; ++f)
        acc = fmaf(xr[1 + f], W0[f * HID + j], acc);
    h[n * HID + j] = bf16r(fmaxf(acc, 0.f));
}

// ---- dual MFMA (N x 128 bf16) @ (128 x 128) -> bf16, LDS-restaged epilogue ----
// Optional fused combine (aggin u32-encoded): A-tile element becomes
// x1 = relu((cnt>0 ? dec(agg)+badd : 0) + h), also written to xout.
__global__ __launch_bounds__(256, 4) void mm_mfma_dual_kernel(const ushort* __restrict__ in,
                                                              const unsigned* __restrict__ aggin,
                                                              const int* __restrict__ cntin,
                                                              const float* __restrict__ baddin,
                                                              ushort* __restrict__ xout,
                                                              const ushort* __restrict__ WuT,
                                                              const ushort* __restrict__ WvT,
                                                              const float* __restrict__ bv,
                                                              ushort* __restrict__ outu,
                                                              ushort* __restrict__ outv, int nrows) {
    __shared__ ushort sH[128 * 136];   // A-tile, then reused for D-restage
    int tid = threadIdx.x;
    int n0 = blockIdx.x * 128;
#pragma unroll
    for (int q = 0; q < 8; ++q) {
        int c = q * 256 + tid;
        int r = c >> 4, off = (c & 15) << 3;
        int n = n0 + r;
        uint4 vv = make_uint4(0, 0, 0, 0);
        if (n < nrows) {
            uint4 hv = *(const uint4*)(in + (size_t)n * HID + off);
            if (aggin) {
                float add[8];
#pragma unroll
                for (int p = 0; p < 8; ++p) add[p] = 0.f;
                if (cntin[n] > 0) {
                    uint4 e0 = *(const uint4*)(aggin + (size_t)n * HID + off);
                    uint4 e1 = *(const uint4*)(aggin + (size_t)n * HID + off + 4);
                    float4 bb0 = *(const float4*)(baddin + off);
                    float4 bb1 = *(const float4*)(baddin + off + 4);
                    add[0] = decf(e0.x) + bb0.x; add[1] = decf(e0.y) + bb0.y;
                    add[2] = decf(e0.z) + bb0.z; add[3] = decf(e0.w) + bb0.w;
                    add[4] = decf(e1.x) + bb1.x; add[5] = decf(e1.y) + bb1.y;
                    add[6] = decf(e1.z) + bb1.z; add[7] = decf(e1.w) + bb1.w;
                }
                unsigned hw[4] = {hv.x, hv.y, hv.z, hv.w};
                unsigned ow[4];
#pragma unroll
                for (int p = 0; p < 4; ++p) {
                    float lo = __uint_as_float(hw[p] << 16);
                    float hi = __uint_as_float(hw[p] & 0xffff0000u);
                    float r0 = fmaxf(add[2 * p] + lo, 0.f);
                    float r1 = fmaxf(add[2 * p + 1] + hi, 0.f);
                    ow[p] = pk_bf16(r0, r1);
                }
                vv = make_uint4(ow[0], ow[1], ow[2], ow[3]);
                *(uint4*)(xout + (size_t)n * HID + off) = vv;
            } else {
                vv = hv;
            }
        }
        *(uint4*)(sH + r * 136 + off) = vv;
    }
    __syncthreads();

    int lane = tid & 63, wv = tid >> 6;
    int l15 = lane & 15, quad = lane >> 4;

    short8 afr[2][4];
#pragma unroll
    for (int rr = 0; rr < 2; ++rr) {
        const ushort* ab = sH + (wv * 32 + rr * 16 + l15) * 136 + quad * 8;
#pragma unroll
        for (int kc = 0; kc < 4; ++kc)
            afr[rr][kc] = *(const short8*)(ab + kc * 32);
    }

#pragma unroll
    for (int pass = 0; pass < 2; ++pass) {
        const ushort* WT = pass ? WvT : WuT;
        ushort* out = pass ? outv : outu;
        f32x4 acc[2][8];
#pragma unroll
        for (int rr = 0; rr < 2; ++rr)
#pragma unroll
            for (int ct = 0; ct < 8; ++ct) acc[rr][ct] = (f32x4){0.f, 0.f, 0.f, 0.f};
#pragma unroll
        for (int kc = 0; kc < 4; ++kc) {
#pragma unroll
            for (int ct = 0; ct < 8; ++ct) {
                short8 bfr = *(const short8*)(WT + (ct * 16 + l15) * 128 + quad * 8 + kc * 32);
                acc[0][ct] = __builtin_amdgcn_mfma_f32_16x16x32_bf16(afr[0][kc], bfr, acc[0][ct], 0, 0, 0);
                acc[1][ct] = __builtin_amdgcn_mfma_f32_16x16x32_bf16(afr[1][kc], bfr, acc[1][ct], 0, 0, 0);
            }
        }
        __syncthreads();
#pragma unroll
        for (int ct = 0; ct < 8; ++ct) {
            int col = ct * 16 + l15;
            float bb = pass ? bv[col] : 0.f;
#pragma unroll
            for (int rr = 0; rr < 2; ++rr) {
                int rowb = wv * 32 + rr * 16 + quad * 4;
#pragma unroll
                for (int reg = 0; reg < 4; ++reg)
                    sH[(rowb + reg) * 136 + col] = bf16r(acc[rr][ct][reg] + bb);
            }
        }
        __syncthreads();
#pragma unroll
        for (int q = 0; q < 8; ++q) {
            int c = q * 256 + tid;
            int r = c >> 4, off = (c & 15) << 3;
            int m = n0 + r;
            if (m < nrows)
                *(uint4*)(out + (size_t)m * HID + off) = *(const uint4*)(sH + r * 136 + off);
        }
    }
}

// ---- merged CSR build for BOTH layers ----
__global__ __launch_bounds__(256) void hist_kernel(const int* __restrict__ dst1,
                                                   const int* __restrict__ dst2,
                                                   int* __restrict__ cnt) {
    int e = blockIdx.x * 256 + threadIdx.x;
    if (e < N_EDGES) atomicAdd(&cnt[dst1[e]], 1);
    else if (e < 2 * N_EDGES) atomicAdd(&cnt[N_NODES + dst2[e - N_EDGES]], 1);
}

__global__ __launch_bounds__(256) void scan1_kernel(const int* __restrict__ cnt,
                                                    int* __restrict__ cursor,
                                                    int* __restrict__ partials) {
    __shared__ int tmp[256];
    int tid = threadIdx.x;
    int gid = blockIdx.x * 256 + tid;
    int v = (gid < 2 * N_NODES) ? cnt[gid] : 0;
    tmp[tid] = v;
    __syncthreads();
#pragma unroll
    for (int off = 1; off < 256; off <<= 1) {
        int t = (tid >= off) ? tmp[tid - off] : 0;
        __syncthreads();
        tmp[tid] += t;
        __syncthreads();
    }
    if (gid < 2 * N_NODES) cursor[gid] = tmp[tid] - v;   // local exclusive
    if (tid == 255) partials[blockIdx.x] = tmp[255];
}

__global__ __launch_bounds__(1024) void scan2_kernel(int* __restrict__ partials) {
    __shared__ int tmp[1024];
    int tid = threadIdx.x;
    int v = (tid < SCAN1_B) ? partials[tid] : 0;
    tmp[tid] = v;
    __syncthreads();
#pragma unroll
    for (int off = 1; off < 1024; off <<= 1) {
        int t = (tid >= off) ? tmp[tid - off] : 0;
        __syncthreads();
        tmp[tid] += t;
        __syncthreads();
    }
    if (tid < SCAN1_B) partials[tid] = tmp[tid] - v;  // exclusive
}

__global__ __launch_bounds__(256) void scatter_kernel(const int* __restrict__ src1,
                                                      const int* __restrict__ dst1,
                                                      const int* __restrict__ src2,
                                                      const int* __restrict__ dst2,
                                                      int* __restrict__ cursor,
                                                      const int* __restrict__ partials,
                                                      int2* __restrict__ pedge) {
    int e = blockIdx.x * 256 + threadIdx.x;
    if (e < N_EDGES) {
        int d = dst1[e];
        int pos = atomicAdd(&cursor[d], 1) + partials[d >> 8];
        pedge[pos] = make_int2(src1[e], d);
    } else if (e < 2 * N_EDGES) {
        int d = dst2[e - N_EDGES];
        int idx = N_NODES + d;
        int pos = atomicAdd(&cursor[idx], 1) + partials[idx >> 8];
        pedge[pos] = make_int2(src2[e - N_EDGES], d);   // pos lands in [N_EDGES, 2*N_EDGES)
    }
}

// ---- zero boundary agg rows for BOTH layers in one launch (u32 arrays) ----
__global__ __launch_bounds__(256) void zbound_both_kernel(const int2* __restrict__ pedge,
                                                          unsigned* __restrict__ agg1,
                                                          unsigned* __restrict__ agg2) {
    int b = blockIdx.x * 4 + (threadIdx.x >> 6);
    int lane = threadIdx.x & 63;
    if (b >= 2 * N_HALF) return;
    int layer = b >= N_HALF;
    int bl = b - layer * N_HALF;
    const int2* pe = pedge + (size_t)layer * N_EDGES;
    unsigned* agg = layer ? agg2 : agg1;
    int d;
    if (bl == 0) {
        d = pe[N_EDGES - 1].y;               // tail row (clamped duplicates -> atomics)
    } else {
        int da = pe[bl * 32 - 1].y, db = pe[bl * 32].y;
        if (da != db) return;
        d = db;
    }
    *(uint2*)(agg + (size_t)d * HID + lane * 2) = make_uint2(0u, 0u);
}

// ---- edge conv: bf16 MFMA, 128-edge dst-sorted windows, 512 threads (R11 config) ----
__global__ __launch_bounds__(512, 4) void edge_kernel(const ushort* __restrict__ u,
                                                      const ushort* __restrict__ v,
                                                      const float* __restrict__ x,
                                                      const int2* __restrict__ pedge,
                                                      const ushort* __restrict__ WbT,
                                                      const float* __restrict__ wlast,
                                                      unsigned* __restrict__ agg) {
    __shared__ ushort sWT[128 * 136];   // 34816 B: WbT[n][k] bf16, padded stride
    __shared__ ushort sU[128 * 136];    // 34816 B union: t[128][136] then msgT[128][132]
    __shared__ int sSrc[128], sDst[128];
    __shared__ float sKd[128];
    __shared__ int sPrev, sNext;
    int tid = threadIdx.x;
    int w0 = blockIdx.x * 128;

#pragma unroll
    for (int q = 0; q < 4; ++q) {
        int c = q * 512 + tid;
        int n = c >> 4, off = (c & 15) << 3;
        *(uint4*)(sWT + n * 136 + off) = *(const uint4*)(WbT + n * 128 + off);
    }
    if (tid < 128) {
        int e = w0 + tid;
        if (e >= N_EDGES) e = N_EDGES - 1;   // clamp: idempotent under max (tail row pre-zeroed)
        int2 sd = pedge[e];
        sSrc[tid] = sd.x;
        sDst[tid] = sd.y;
        sKd[tid] = x[(size_t)sd.x * 16] - x[(size_t)sd.y * 16];
    }
    if (tid == 128) sPrev = (w0 > 0) ? pedge[w0 - 1].y : -1;
    if (tid == 129) sNext = (w0 + 128 < N_EDGES) ? pedge[w0 + 128].y : -1;
    __syncthreads();

    // phase 1: 4 threads/edge, 32 cols each (512 threads -> 128 edges)
    {
        int eloc = tid >> 2;
        int kb = (tid & 3) << 5;
        int s = sSrc[eloc], d = sDst[eloc];
        float kd = sKd[eloc];
        const uint4* ur = (const uint4*)(u + (size_t)s * HID + kb);
        const uint4* vr = (const uint4*)(v + (size_t)d * HID + kb);
        uint4 uu[4], vv[4];
#pragma unroll
        for (int q = 0; q < 4; ++q) uu[q] = ur[q];
#pragma unroll
        for (int q = 0; q < 4; ++q) vv[q] = vr[q];
        const float4* wr4 = (const float4*)(wlast + kb);
        uint4* tout = (uint4*)(sU + eloc * 136 + kb);
#pragma unroll
        for (int q = 0; q < 4; ++q) {
            float4 wa = wr4[2 * q], wb = wr4[2 * q + 1];
            float w[8] = {wa.x, wa.y, wa.z, wa.w, wb.x, wb.y, wb.z, wb.w};
            unsigned pu[4] = {uu[q].x, uu[q].y, uu[q].z, uu[q].w};
            unsigned pv[4] = {vv[q].x, vv[q].y, vv[q].z, vv[q].w};
            unsigned pk[4];
#pragma unroll
            for (int p = 0; p < 4; ++p) {
                float a0 = __uint_as_float(pu[p] << 16) + __uint_as_float(pv[p] << 16);
                float a1 = __uint_as_float(pu[p] & 0xffff0000u) + __uint_as_float(pv[p] & 0xffff0000u);
                a0 = fmaf(kd, w[2 * p], a0);
                a1 = fmaf(kd, w[2 * p + 1], a1);
                a0 = a0 > 0.f ? a0 : 0.1f * a0;
                a1 = a1 > 0.f ? a1 : 0.1f * a1;
                pk[p] = pk_bf16(a0, a1);
            }
            uint4 o; o.x = pk[0]; o.y = pk[1]; o.z = pk[2]; o.w = pk[3];
            tout[q] = o;
        }
    }
    __syncthreads();

    // phase 2: MFMA. wave wv (0..7) owns edges wv*16..+15; 8 col-tiles x 4 K-chunks
    int lane = tid & 63, wv = tid >> 6;
    int l15 = lane & 15, quad = lane >> 4;
    short8 afr[4];
    {
        const ushort* ab = sU + (wv * 16 + l15) * 136 + quad * 8;
#pragma unroll
        for (int kc = 0; kc < 4; ++kc)
            afr[kc] = *(const short8*)(ab + kc * 32);
    }
    f32x4 acc[8];
#pragma unroll
    for (int ct = 0; ct < 8; ++ct) {
        f32x4 a = {0.f, 0.f, 0.f, 0.f};
        const ushort* bb = sWT + (ct * 16 + l15) * 136 + quad * 8;
#pragma unroll
        for (int kc = 0; kc < 4; ++kc) {
            short8 bfr = *(const short8*)(bb + kc * 32);
            a = __builtin_amdgcn_mfma_f32_16x16x32_bf16(afr[kc], bfr, a, 0, 0, 0);
        }
        acc[ct] = a;
    }
    __syncthreads();   // all t reads done -> sU reusable

    // epilogue: msgT[col][edge] bf16, stride 132
#pragma unroll
    for (int ct = 0; ct < 8; ++ct) {
        uint2 pr;
        pr.x = pk_bf16(acc[ct][0], acc[ct][1]);
        pr.y = pk_bf16(acc[ct][2], acc[ct][3]);
        *(uint2*)(sU + (ct * 16 + l15) * 132 + wv * 16 + quad * 4) = pr;
    }
    __syncthreads();

    // phase 3: segmented max, 4 threads/col (quarter-window = 32 edges each)
    {
        int j = tid & 127;
        int q4 = tid >> 7;            // 0..3
        int eBeg = q4 * 32;
        const ushort* mrow = sU + j * 132 + eBeg;
        float vals[32];
#pragma unroll
        for (int q = 0; q < 8; ++q) {
            ushort4 mv = *(const ushort4*)(mrow + q * 4);
            vals[q * 4 + 0] = bf2f(mv.x);
            vals[q * 4 + 1] = bf2f(mv.y);
            vals[q * 4 + 2] = bf2f(mv.z);
            vals[q * 4 + 3] = bf2f(mv.w);
        }
        int prevD = (q4 == 0) ? sPrev : sDst[eBeg - 1];
        int nextD = (q4 == 3) ? sNext : sDst[eBeg + 32];
        int cur = sDst[eBeg], rs = eBeg;
        float mx = vals[0];
        for (int e2 = 1; e2 < 32; ++e2) {
            int d = sDst[eBeg + e2];      // uniform across the quarter's lanes
            float vv2 = vals[e2];
            if (d != cur) {
                unsigned en = encf(mx);
                unsigned* ap = agg + (size_t)cur * HID + j;
                if (rs == eBeg && cur == prevD) atomicMax(ap, en);
                else *ap = en;
                cur = d; rs = eBeg + e2; mx = vv2;
            } else {
                mx = fmaxf(mx, vv2);
            }
        }
        unsigned en = encf(mx);
        unsigned* ap = agg + (size_t)cur * HID + j;
        if ((rs == eBeg && cur == prevD) || cur == nextD) atomicMax(ap, en);
        else *ap = en;
    }
}

// ---- pooling with fused layer-2 combine: x2 never materialized ----
__global__ __launch_bounds__(256) void pool_kernel(const ushort* __restrict__ x1,
                                                   const unsigned* __restrict__ agg2,
                                                   const float* __restrict__ b2b,
                                                   const int* __restrict__ cnt2,
                                                   const int* __restrict__ batch,
                                                   float* __restrict__ pooled) {
    int g = blockIdx.x >> 3, s = blockIdx.x & 7;
    int tid = threadIdx.x;
    int lo = 0, hi = N_NODES;
    while (lo < hi) { int mid = (lo + hi) >> 1; if (batch[mid] < g) lo = mid + 1; else hi = mid; }
    int start = lo;
    hi = N_NODES;
    while (lo < hi) { int mid = (lo + hi) >> 1; if (batch[mid] < g + 1) lo = mid + 1; else hi = mid; }
    int end = lo;
    int cnt = end - start;
    int b0 = start + (int)((long long)cnt * s / 8);
    int b1 = start + (int)((long long)cnt * (s + 1) / 8);
    if (b1 <= b0) return;
    int j = tid & 127;
    bool isx2 = tid >= 128;
    float bbj = isx2 ? b2b[j] : 0.f;
    float mx = -INFINITY, sm = 0.f;
    for (int n = b0; n < b1; ++n) {
        float xv = bf2f(x1[(size_t)n * HID + j]);
        float vv;
        if (isx2) {
            float a = 0.f;
            if (cnt2[n] > 0) a = decf(agg2[(size_t)n * HID + j]) + bbj;
            vv = fmaxf(a + xv, 0.f);
        } else {
            vv = xv;
        }
        mx = fmaxf(mx, vv);
        sm += vv;
    }
    atomicMax((unsigned*)pooled + (size_t)g * 512 + tid, encf(mx));
    atomicAdd(pooled + (size_t)g * 512 + 256 + tid, sm);
}

// ---- final MLP + log_softmax ----
__global__ __launch_bounds__(128) void final_kernel(const float* __restrict__ pooled,
                                                    const int* __restrict__ batch,
                                                    const float* __restrict__ Wf1,
                                                    const float* __restrict__ bf1,
                                                    const float* __restrict__ Wf2,
                                                    const float* __restrict__ bf2,
                                                    float* __restrict__ out) {
    __shared__ float sP[512];
    __shared__ float sH[128];
    int g = blockIdx.x, tid = threadIdx.x;
    int lo = 0, hi = N_NODES;
    while (lo < hi) { int mid = (lo + hi) >> 1; if (batch[mid] < g) lo = mid + 1; else hi = mid; }
    int start = lo;
    hi = N_NODES;
    while (lo < hi) { int mid = (lo + hi) >> 1; if (batch[mid] < g + 1) lo = mid + 1; else hi = mid; }
    int cnt = lo - start;
    float inv = 1.f / (float)(cnt > 1 ? cnt : 1);
#pragma unroll
    for (int q = 0; q < 4; ++q) {
        int idx = q * 128 + tid;
        float raw;
        if (idx < 256) {
            unsigned e = ((const unsigned*)pooled)[(size_t)g * 512 + idx];
            raw = (e == 0u) ? 0.f : decf(e);
        } else {
            raw = pooled[(size_t)g * 512 + idx] * inv;
        }
        sP[idx] = raw;
    }
    __syncthreads();
    float acc = bf1[tid];
    for (int k = 0; k < 512; ++k) acc = fmaf(sP[k], Wf1[k * HID + tid], acc);
    sH[tid] = fmaxf(acc, 0.f);
    __syncthreads();
    if (tid < 2) {
        float l = bf2[tid];
        for (int k = 0; k < 128; ++k) l = fmaf(sH[k], Wf2[k * 2 + tid], l);
        sP[tid] = l;
    }
    __syncthreads();
    if (tid == 0) {
        float l0 = sP[0], l1 = sP[1];
        float m = fmaxf(l0, l1);
        float ls = m + logf(expf(l0 - m) + expf(l1 - m));
        out[g * 2 + 0] = l0 - ls;
        out[g * 2 + 1] = l1 - ls;
    }
}

extern "C" void kernel_launch(void* const* d_in, const int* in_sizes, int n_in,
                              void* d_out, int out_size, void* d_ws, size_t ws_size,
                              hipStream_t stream) {
    const float* x     = (const float*)d_in[0];
    const float* W_enc = (const float*)d_in[1];
    const float* b_enc = (const float*)d_in[2];
    const float* W0    = (const float*)d_in[3];
    const float* b0    = (const float*)d_in[4];
    const float* W1a   = (const float*)d_in[5];
    const float* b1a   = (const float*)d_in[6];
    const float* W1b   = (const float*)d_in[7];
    const float* b1b   = (const float*)d_in[8];
    const float* W2a   = (const float*)d_in[9];
    const float* b2a   = (const float*)d_in[10];
    const float* W2b   = (const float*)d_in[11];
    const float* b2b   = (const float*)d_in[12];
    const float* Wf1   = (const float*)d_in[13];
    const float* bf1   = (const float*)d_in[14];
    const float* Wf2   = (const float*)d_in[15];
    const float* bf2   = (const float*)d_in[16];
    const int* src1    = (const int*)d_in[17];
    const int* dst1    = (const int*)d_in[18];
    const int* src2    = (const int*)d_in[19];
    const int* dst2    = (const int*)d_in[20];
    const int* batch   = (const int*)d_in[21];

    const size_t NB = (size_t)N_NODES * HID;     // 12.8M elements
    ushort* hbuf  = (ushort*)d_ws;               // h -> x1 (in place, bf16)
    unsigned* agg1 = (unsigned*)(hbuf + NB);     // layer-1 segment-max (u32 encoded)
    unsigned* agg2 = agg1 + NB;                  // layer-2 segment-max
    ushort* ubuf  = (ushort*)(agg2 + NB);        // u bf16
    ushort* vbuf  = ubuf + NB;                   // v bf16
    ushort* WT    = vbuf + NB;                   // 6 x 16384 bf16: Wb1,Wb2,Wu1,Wv1,Wu2,Wv2
    ushort* WbT1 = WT;
    ushort* WbT2 = WT + 1 * HID * HID;
    ushort* WuT1 = WT + 2 * HID * HID;
    ushort* WvT1 = WT + 3 * HID * HID;
    ushort* WuT2 = WT + 4 * HID * HID;
    ushort* WvT2 = WT + 5 * HID * HID;
    float* wkey  = (float*)(WT + 6 * HID * HID);
    float* bias0 = wkey + 128;
    float* pooled = bias0 + 128;                 // 128*512 fp32
    int* cnt    = (int*)(pooled + 128 * 512);    // 2*N_NODES (both layers)
    int* cursor = cnt + 2 * N_NODES;             // 2*N_NODES
    int* partials = cursor + 2 * N_NODES;        // 1024
    int2* pedge = (int2*)(partials + 1024);      // 2*N_EDGES pairs (both layers)

    const int bothGrid = (2 * N_EDGES + 255) / 256;   // 3907
    const int edgeGrid = (N_EDGES + 127) / 128;       // 3907 windows of 128
    const int mmGrid   = (N_NODES + 127) / 128;       // 782
    const int zbGrid   = (2 * N_HALF + 3) / 4;        // 7813 (both layers)

    transp_prep_kernel<<<385, 256, 0, stream>>>(W1b, W2b, W1a, W2a, W_enc, b_enc, W0, b0,
                                                WT, wkey, bias0);
    encode_kernel<<<N_NODES / 2, 256, 0, stream>>>(x, W0, wkey, bias0, hbuf);

    // ---- merged CSR build (both layers) ----
    hipMemsetAsync(cnt, 0, 2 * N_NODES * sizeof(int), stream);
    hist_kernel<<<bothGrid, 256, 0, stream>>>(dst1, dst2, cnt);
    scan1_kernel<<<SCAN1_B, 256, 0, stream>>>(cnt, cursor, partials);
    scan2_kernel<<<1, 1024, 0, stream>>>(partials);
    scatter_kernel<<<bothGrid, 256, 0, stream>>>(src1, dst1, src2, dst2, cursor, partials, pedge);
    zbound_both_kernel<<<zbGrid, 256, 0, stream>>>(pedge, agg1, agg2);

    // ---- layer 1 ----
    mm_mfma_dual_kernel<<<mmGrid, 256, 0, stream>>>(hbuf, nullptr, nullptr, nullptr, nullptr,
                                                    WuT1, WvT1, b1a, ubuf, vbuf, N_NODES);
    edge_kernel<<<edgeGrid, 512, 0, stream>>>(ubuf, vbuf, x, pedge, WbT1, W1a + 256 * HID, agg1);

    // ---- layer 2 (mm fuses layer-1 combine; writes x1 to hbuf) ----
    mm_mfma_dual_kernel<<<mmGrid, 256, 0, stream>>>(hbuf, agg1, cnt, b1b, hbuf,
                                                    WuT2, WvT2, b2a, ubuf, vbuf, N_NODES);
    edge_kernel<<<edgeGrid, 512, 0, stream>>>(ubuf, vbuf, x, pedge + N_EDGES, WbT2, W2a + 256 * HID, agg2);

    // ---- pooling (layer-2 combine fused) + head ----
    hipMemsetAsync(pooled, 0, 128 * 512 * sizeof(float), stream);
    pool_kernel<<<N_GRAPHS * 8, 256, 0, stream>>>(hbuf, agg2, b2b, cnt + N_NODES, batch, pooled);
    final_kernel<<<N_GRAPHS, 128, 0, stream>>>(pooled, batch, Wf1, bf1, Wf2, bf2, (float*)d_out);
}